// Round 5
// baseline (350.083 us; speedup 1.0000x reference)
//
#include <hip/hip_runtime.h>
#include <hip/hip_bf16.h>
#include <stdint.h>

typedef __bf16 bf16;
typedef __bf16 bf16x4 __attribute__((ext_vector_type(4)));
typedef __bf16 bf16x8 __attribute__((ext_vector_type(8)));
typedef float f32x4 __attribute__((ext_vector_type(4)));

// ---------------------------------------------------------------------------
// Kernel 1: fused RMSNorm (F.normalize * sqrt(1024) * gamma) + gate GEMV+sigmoid
// one block (256 thr) per row of x [8192, 1024]. Inputs fp32, xn written bf16.
// ---------------------------------------------------------------------------
__global__ __launch_bounds__(256) void rmsnorm_gates_kernel(
    const float* __restrict__ x, const float* __restrict__ gamma,
    const float* __restrict__ Wg, const float* __restrict__ bg,
    bf16* __restrict__ xn, float* __restrict__ gates) {
  __shared__ float wss[4];
  __shared__ float red[256][17];  // +1 pad: breaks 16-stride bank conflicts
  const int t = threadIdx.x;
  const size_t row = blockIdx.x;
  const float* xr = x + row * 1024;

  float4 xv = *(const float4*)&xr[t * 4];
  float v[4] = {xv.x, xv.y, xv.z, xv.w};
  float ss = v[0]*v[0] + v[1]*v[1] + v[2]*v[2] + v[3]*v[3];
#pragma unroll
  for (int mm = 1; mm < 64; mm <<= 1) ss += __shfl_xor(ss, mm);
  if ((t & 63) == 0) wss[t >> 6] = ss;
  __syncthreads();
  ss = wss[0] + wss[1] + wss[2] + wss[3];
  float inv = 32.0f / sqrtf(fmaxf(ss, 1e-24f));  // sqrt(1024)=32

  float4 gv = *(const float4*)&gamma[t * 4];
  float gvv[4] = {gv.x, gv.y, gv.z, gv.w};
  float xf[4];
  bf16x4 outv;
#pragma unroll
  for (int i = 0; i < 4; ++i) {
    xf[i] = v[i] * inv * gvv[i];
    outv[i] = (bf16)xf[i];
  }
  *(bf16x4*)&xn[row * 1024 + t * 4] = outv;

  // gates = xn @ Wg[1024,16] + bg, then sigmoid (computed in fp32)
  float ph[16];
#pragma unroll
  for (int hh = 0; hh < 16; ++hh) ph[hh] = 0.f;
#pragma unroll
  for (int i = 0; i < 4; ++i) {
    const float* wr2 = Wg + (size_t)(t * 4 + i) * 16;
#pragma unroll
    for (int q4 = 0; q4 < 4; ++q4) {
      float4 wv = *(const float4*)&wr2[q4 * 4];
      ph[q4 * 4 + 0] += xf[i] * wv.x;
      ph[q4 * 4 + 1] += xf[i] * wv.y;
      ph[q4 * 4 + 2] += xf[i] * wv.z;
      ph[q4 * 4 + 3] += xf[i] * wv.w;
    }
  }
#pragma unroll
  for (int hh = 0; hh < 16; ++hh) red[t][hh] = ph[hh];
  __syncthreads();
  for (int sN = 128; sN > 0; sN >>= 1) {
    if (t < sN) {
#pragma unroll
      for (int hh = 0; hh < 16; ++hh) red[t][hh] += red[t + sN][hh];
    }
    __syncthreads();
  }
  if (t < 16) {
    float gg = red[0][t] + bg[t];
    gates[row * 16 + t] = 1.f / (1.f + __expf(-gg));
  }
}

// ---------------------------------------------------------------------------
// Kernel 2: fp32 -> bf16 transpose (for B^T GEMM operand), 32x32 tiles
// ---------------------------------------------------------------------------
__global__ void transpose_f32_bf16(const float* __restrict__ in, bf16* __restrict__ out,
                                   int R, int C) {
  __shared__ bf16 tile[32][33];
  const int tx = threadIdx.x, ty = threadIdx.y;  // 32 x 8
  const int c0 = blockIdx.x * 32, r0 = blockIdx.y * 32;
#pragma unroll
  for (int i = 0; i < 32; i += 8)
    tile[ty + i][tx] = (bf16)in[(size_t)(r0 + ty + i) * C + c0 + tx];
  __syncthreads();
#pragma unroll
  for (int i = 0; i < 32; i += 8)
    out[(size_t)(c0 + ty + i) * R + r0 + tx] = tile[tx][ty + i];
}

// ---------------------------------------------------------------------------
// Kernel 3: MFMA bf16 GEMM, C[M,N] = A[M,K] @ Bt[N,K]^T, 128x128 tile, BK=32.
// Templated output type: bf16 for intermediates, float for d_out (fp32 buffer!).
// ---------------------------------------------------------------------------
template <typename OutT>
__global__ __launch_bounds__(256) void gemm_bt_128(
    const bf16* __restrict__ A, const bf16* __restrict__ Bt,
    OutT* __restrict__ C, int M, int N, int K) {
  __shared__ bf16 lA[128 * 32];
  __shared__ bf16 lB[128 * 32];
  const int t = threadIdx.x;
  const int w = t >> 6, lane = t & 63;
  const int col0 = lane & 15, quad = lane >> 4;
  const int m0 = blockIdx.y * 128, n0 = blockIdx.x * 128;
  const int wr = (w >> 1) * 64, wc = (w & 1) * 64;

  const int srow = t >> 2;          // staging row (0..63)
  const int soff = (t & 3) << 3;    // staging k-offset (0,8,16,24)

  f32x4 acc[4][4] = {};

  for (int k0 = 0; k0 < K; k0 += 32) {
    // prefetch to registers before the barrier (overlap with prior compute)
    bf16x8 va0 = *(const bf16x8*)&A [(size_t)(m0 +      srow) * K + k0 + soff];
    bf16x8 va1 = *(const bf16x8*)&A [(size_t)(m0 + 64 + srow) * K + k0 + soff];
    bf16x8 vb0 = *(const bf16x8*)&Bt[(size_t)(n0 +      srow) * K + k0 + soff];
    bf16x8 vb1 = *(const bf16x8*)&Bt[(size_t)(n0 + 64 + srow) * K + k0 + soff];
    __syncthreads();  // previous iteration's LDS reads done
    *(bf16x8*)&lA[(     srow) * 32 + soff] = va0;
    *(bf16x8*)&lA[(64 + srow) * 32 + soff] = va1;
    *(bf16x8*)&lB[(     srow) * 32 + soff] = vb0;
    *(bf16x8*)&lB[(64 + srow) * 32 + soff] = vb1;
    __syncthreads();  // staged tiles visible

    bf16x8 af[4], bfr[4];
#pragma unroll
    for (int i = 0; i < 4; ++i)
      af[i] = *(const bf16x8*)&lA[(wr + i * 16 + col0) * 32 + quad * 8];
#pragma unroll
    for (int j = 0; j < 4; ++j)
      bfr[j] = *(const bf16x8*)&lB[(wc + j * 16 + col0) * 32 + quad * 8];
#pragma unroll
    for (int i = 0; i < 4; ++i)
#pragma unroll
      for (int j = 0; j < 4; ++j)
        acc[i][j] = __builtin_amdgcn_mfma_f32_16x16x32_bf16(af[i], bfr[j], acc[i][j], 0, 0, 0);
  }

  // epilogue: C/D layout col=lane&15, row=quad*4+reg (m89-verified)
#pragma unroll
  for (int i = 0; i < 4; ++i)
#pragma unroll
    for (int j = 0; j < 4; ++j)
#pragma unroll
      for (int r = 0; r < 4; ++r) {
        int row = m0 + wr + i * 16 + quad * 4 + r;
        int col = n0 + wc + j * 16 + col0;
        C[(size_t)row * N + col] = (OutT)acc[i][j][r];
      }
}

// ---------------------------------------------------------------------------
// Kernel 4: sliding-window attention, one block per (b, h, 64-query group)
// context = 320 keys [qs-256, qs+63]; valid keys for query i: max(0,i-256)..i
// ---------------------------------------------------------------------------
#define NEG_BIG -1e30f
__global__ __launch_bounds__(256) void attn_kernel(
    const bf16* __restrict__ qkv, const float* __restrict__ gates,
    bf16* __restrict__ attnO) {
  __shared__ bf16 lQ[64 * 64];     // 8 KB
  __shared__ bf16 lKV[320 * 64];   // 40 KB: K[320][64] phase1, Vt[64][320] phase2
  __shared__ bf16 lP[4 * 16 * 32]; // 4 KB: per-wave P C->A layout scratch

  const int t = threadIdx.x;
  const int w = t >> 6, lane = t & 63;
  const int col0 = lane & 15, quad = lane >> 4;

  const int blk = blockIdx.x;
  const int g = blk & 63;
  const int h = (blk >> 6) & 15;
  const int bb = blk >> 10;
  const int qs = g * 64;

  const size_t rs = 3072;
  const bf16* qbase = qkv + ((size_t)bb * 4096) * rs + h * 64;

  // stage Q [64][64]
  for (int c = t; c < 64 * 8; c += 256) {
    int row = c >> 3, off = (c & 7) * 8;
    *(uint4*)&lQ[row * 64 + off] =
        *(const uint4*)(qbase + (size_t)(qs + row) * rs + off);
  }
  // stage K [320][64] (zero-fill j<0)
  for (int c = t; c < 320 * 8; c += 256) {
    int row = c >> 3, off = (c & 7) * 8;
    int j = qs - 256 + row;
    uint4 val = {0, 0, 0, 0};
    if (j >= 0) val = *(const uint4*)(qbase + 1024 + (size_t)j * rs + off);
    *(uint4*)&lKV[row * 64 + off] = val;
  }
  __syncthreads();

  // QK^T: wave w owns queries [w*16, w*16+16); S tile per wave: [16, 320]
  bf16x8 a0 = *(const bf16x8*)&lQ[(w * 16 + col0) * 64 + quad * 8];
  bf16x8 a1 = *(const bf16x8*)&lQ[(w * 16 + col0) * 64 + 32 + quad * 8];
  f32x4 s[20];
#pragma unroll
  for (int kt = 0; kt < 20; ++kt) {
    bf16x8 b0 = *(const bf16x8*)&lKV[(kt * 16 + col0) * 64 + quad * 8];
    bf16x8 b1 = *(const bf16x8*)&lKV[(kt * 16 + col0) * 64 + 32 + quad * 8];
    f32x4 z = {};
    z = __builtin_amdgcn_mfma_f32_16x16x32_bf16(a0, b0, z, 0, 0, 0);
    z = __builtin_amdgcn_mfma_f32_16x16x32_bf16(a1, b1, z, 0, 0, 0);
    s[kt] = z;
  }
  __syncthreads();  // all waves done reading K from lKV

  // stage V transposed: Vt[d][c] (zero-fill j<0) — overwrites lKV
  for (int c = t; c < 320 * 8; c += 256) {
    int row = c >> 3, off = (c & 7) * 8;
    int j = qs - 256 + row;
    bf16 tmp[8];
    if (j >= 0) {
      *(uint4*)tmp = *(const uint4*)(qbase + 2048 + (size_t)j * rs + off);
    } else {
#pragma unroll
      for (int d2 = 0; d2 < 8; ++d2) tmp[d2] = (bf16)0.f;
    }
#pragma unroll
    for (int d2 = 0; d2 < 8; ++d2) lKV[(off + d2) * 320 + row] = tmp[d2];
  }

  // softmax in registers (C layout: query row = quad*4+r, key col = kt*16+col0)
  float mrow[4] = {NEG_BIG, NEG_BIG, NEG_BIG, NEG_BIG};
  float lrow[4] = {0, 0, 0, 0};
#pragma unroll
  for (int kt = 0; kt < 20; ++kt) {
    int c = kt * 16 + col0;
#pragma unroll
    for (int r = 0; r < 4; ++r) {
      int ql = w * 16 + quad * 4 + r;
      bool valid = (c >= ql) && (c <= ql + 256) && (qs - 256 + c >= 0);
      float sv = valid ? s[kt][r] * 0.125f : NEG_BIG;  // scale = 1/sqrt(64)
      s[kt][r] = sv;
      mrow[r] = fmaxf(mrow[r], sv);
    }
  }
#pragma unroll
  for (int mm = 1; mm < 16; mm <<= 1)
#pragma unroll
    for (int r = 0; r < 4; ++r) mrow[r] = fmaxf(mrow[r], __shfl_xor(mrow[r], mm));
#pragma unroll
  for (int kt = 0; kt < 20; ++kt)
#pragma unroll
    for (int r = 0; r < 4; ++r) {
      float p = __expf(s[kt][r] - mrow[r]);
      s[kt][r] = p;
      lrow[r] += p;
    }
#pragma unroll
  for (int mm = 1; mm < 16; mm <<= 1)
#pragma unroll
    for (int r = 0; r < 4; ++r) lrow[r] += __shfl_xor(lrow[r], mm);

  __syncthreads();  // Vt staged

  // PV: per 32-key chunk, C->A layout transpose through per-wave LDS scratch.
  f32x4 o[4] = {};
  bf16* pw = &lP[w * 512];
  for (int kc = 0; kc < 10; ++kc) {
    __syncthreads();  // prior iteration's pa reads complete before overwrite
#pragma unroll
    for (int r = 0; r < 4; ++r) {
      pw[(quad * 4 + r) * 32 + col0]      = (bf16)s[2 * kc][r];
      pw[(quad * 4 + r) * 32 + 16 + col0] = (bf16)s[2 * kc + 1][r];
    }
    __syncthreads();  // P chunk visible in A-layout order
    bf16x8 pa = *(const bf16x8*)&pw[col0 * 32 + quad * 8];
#pragma unroll
    for (int n = 0; n < 4; ++n) {
      bf16x8 bv = *(const bf16x8*)&lKV[(n * 16 + col0) * 320 + kc * 32 + quad * 8];
      o[n] = __builtin_amdgcn_mfma_f32_16x16x32_bf16(pa, bv, o[n], 0, 0, 0);
    }
  }

  // epilogue: divide by l, apply sigmoid gate, write [b, s, h*64+d]
#pragma unroll
  for (int r = 0; r < 4; ++r) {
    int ql = w * 16 + quad * 4 + r;
    int srow = qs + ql;
    float gate = gates[((size_t)bb * 4096 + srow) * 16 + h];
    float scale = gate / lrow[r];
#pragma unroll
    for (int n = 0; n < 4; ++n)
      attnO[((size_t)bb * 4096 + srow) * 1024 + h * 64 + n * 16 + col0] =
          (bf16)(o[n][r] * scale);
  }
}

// ---------------------------------------------------------------------------
extern "C" void kernel_launch(void* const* d_in, const int* in_sizes, int n_in,
                              void* d_out, int out_size, void* d_ws, size_t ws_size,
                              hipStream_t stream) {
  // Inputs fp32, mapped by flat element count (all six sizes distinct).
  const float *x = nullptr, *gamma = nullptr, *Wqkv = nullptr,
              *Wg = nullptr, *bg = nullptr, *Wout = nullptr;
  for (int i = 0; i < n_in; ++i) {
    switch (in_sizes[i]) {
      case 8388608: x     = (const float*)d_in[i]; break;
      case 1024:    gamma = (const float*)d_in[i]; break;
      case 3145728: Wqkv  = (const float*)d_in[i]; break;
      case 16384:   Wg    = (const float*)d_in[i]; break;
      case 16:      bg    = (const float*)d_in[i]; break;
      case 1048576: Wout  = (const float*)d_in[i]; break;
    }
  }
  // OUTPUT IS FP32 (reference returns fp32; R3<->R4 bit-identical absmax
  // proved the compute and implicated the output dtype).
  float* out = (float*)d_out;

  char* ws = (char*)d_ws;
  bf16* qkv   = (bf16*)ws;  ws += (size_t)8192 * 3072 * 2;   // 48 MB
  bf16* xn    = (bf16*)ws;                                    // 16 MB, dead after QKV GEMM
  bf16* attnO = (bf16*)ws;  ws += (size_t)8192 * 1024 * 2;   // aliases xn (stream-ordered)
  float* gates= (float*)ws; ws += (size_t)8192 * 16 * 4;
  bf16* WqkvT = (bf16*)ws;  ws += (size_t)3072 * 1024 * 2;
  bf16* WoutT = (bf16*)ws;  ws += (size_t)1024 * 1024 * 2;   // total ~72.5 MB

  rmsnorm_gates_kernel<<<8192, 256, 0, stream>>>(x, gamma, Wg, bg, xn, gates);
  transpose_f32_bf16<<<dim3(3072 / 32, 1024 / 32), dim3(32, 8), 0, stream>>>(Wqkv, WqkvT, 1024, 3072);
  transpose_f32_bf16<<<dim3(1024 / 32, 1024 / 32), dim3(32, 8), 0, stream>>>(Wout, WoutT, 1024, 1024);
  gemm_bt_128<bf16><<<dim3(3072 / 128, 8192 / 128), 256, 0, stream>>>(xn, WqkvT, qkv, 8192, 3072, 1024);
  attn_kernel<<<2048, 256, 0, stream>>>(qkv, gates, attnO);
  gemm_bt_128<float><<<dim3(1024 / 128, 8192 / 128), 256, 0, stream>>>(attnO, WoutT, out, 8192, 1024, 1024);
}

// Round 6
// 302.800 us; speedup vs baseline: 1.1562x; 1.1562x over previous
//
#include <hip/hip_runtime.h>
#include <hip/hip_bf16.h>
#include <stdint.h>

typedef __bf16 bf16;
typedef __bf16 bf16x4 __attribute__((ext_vector_type(4)));
typedef __bf16 bf16x8 __attribute__((ext_vector_type(8)));
typedef float f32x4 __attribute__((ext_vector_type(4)));

// ---------------------------------------------------------------------------
// Kernel 1: pure streaming RMSNorm (F.normalize * sqrt(1024) * gamma).
// Gates are now fused into the QKV GEMM (16 extra N-columns).
// one block (256 thr) per row of x [8192, 1024]. Inputs fp32, xn written bf16.
// ---------------------------------------------------------------------------
__global__ __launch_bounds__(256) void rmsnorm_kernel(
    const float* __restrict__ x, const float* __restrict__ gamma,
    bf16* __restrict__ xn) {
  __shared__ float wss[4];
  const int t = threadIdx.x;
  const size_t row = blockIdx.x;
  const float* xr = x + row * 1024;

  float4 xv = *(const float4*)&xr[t * 4];
  float v[4] = {xv.x, xv.y, xv.z, xv.w};
  float ss = v[0]*v[0] + v[1]*v[1] + v[2]*v[2] + v[3]*v[3];
#pragma unroll
  for (int mm = 1; mm < 64; mm <<= 1) ss += __shfl_xor(ss, mm);
  if ((t & 63) == 0) wss[t >> 6] = ss;
  __syncthreads();
  ss = wss[0] + wss[1] + wss[2] + wss[3];
  float inv = 32.0f / sqrtf(fmaxf(ss, 1e-24f));  // sqrt(1024)=32

  float4 gv = *(const float4*)&gamma[t * 4];
  float gvv[4] = {gv.x, gv.y, gv.z, gv.w};
  bf16x4 outv;
#pragma unroll
  for (int i = 0; i < 4; ++i) outv[i] = (bf16)(v[i] * inv * gvv[i]);
  *(bf16x4*)&xn[row * 1024 + t * 4] = outv;
}

// ---------------------------------------------------------------------------
// Kernel 2: fp32 -> bf16 transpose (for B^T GEMM operand), 32x32 tiles
// ---------------------------------------------------------------------------
__global__ void transpose_f32_bf16(const float* __restrict__ in, bf16* __restrict__ out,
                                   int R, int C) {
  __shared__ bf16 tile[32][33];
  const int tx = threadIdx.x, ty = threadIdx.y;  // 32 x 8
  const int c0 = blockIdx.x * 32, r0 = blockIdx.y * 32;
#pragma unroll
  for (int i = 0; i < 32; i += 8)
    tile[ty + i][tx] = (bf16)in[(size_t)(r0 + ty + i) * C + c0 + tx];
  __syncthreads();
#pragma unroll
  for (int i = 0; i < 32; i += 8)
    out[(size_t)(c0 + ty + i) * R + r0 + tx] = tile[tx][ty + i];
}

// Wg [1024,16] -> rows 3072..3087 of BtAug [3200,1024]. Tiny (16K elements).
__global__ __launch_bounds__(256) void wg_transpose(const float* __restrict__ Wg,
                                                    bf16* __restrict__ BtAug) {
  int idx = blockIdx.x * 256 + threadIdx.x;   // [0, 16384)
  int n = idx >> 10, k = idx & 1023;
  BtAug[(size_t)(3072 + n) * 1024 + k] = (bf16)Wg[(size_t)k * 16 + n];
}

// ---------------------------------------------------------------------------
// Kernel 3: MFMA bf16 GEMM, C[M,N] = A[M,K] @ Bt[N,K]^T, 128x128 tile, BK=32.
// Templated output type: bf16 for intermediates, float for d_out (fp32 buffer).
// ---------------------------------------------------------------------------
template <typename OutT>
__global__ __launch_bounds__(256) void gemm_bt_128(
    const bf16* __restrict__ A, const bf16* __restrict__ Bt,
    OutT* __restrict__ C, int M, int N, int K) {
  __shared__ bf16 lA[128 * 32];
  __shared__ bf16 lB[128 * 32];
  const int t = threadIdx.x;
  const int w = t >> 6, lane = t & 63;
  const int col0 = lane & 15, quad = lane >> 4;
  const int m0 = blockIdx.y * 128, n0 = blockIdx.x * 128;
  const int wr = (w >> 1) * 64, wc = (w & 1) * 64;

  const int srow = t >> 2;          // staging row (0..63)
  const int soff = (t & 3) << 3;    // staging k-offset (0,8,16,24)

  f32x4 acc[4][4] = {};

  for (int k0 = 0; k0 < K; k0 += 32) {
    // prefetch to registers before the barrier (overlap with prior compute)
    bf16x8 va0 = *(const bf16x8*)&A [(size_t)(m0 +      srow) * K + k0 + soff];
    bf16x8 va1 = *(const bf16x8*)&A [(size_t)(m0 + 64 + srow) * K + k0 + soff];
    bf16x8 vb0 = *(const bf16x8*)&Bt[(size_t)(n0 +      srow) * K + k0 + soff];
    bf16x8 vb1 = *(const bf16x8*)&Bt[(size_t)(n0 + 64 + srow) * K + k0 + soff];
    __syncthreads();  // previous iteration's LDS reads done
    *(bf16x8*)&lA[(     srow) * 32 + soff] = va0;
    *(bf16x8*)&lA[(64 + srow) * 32 + soff] = va1;
    *(bf16x8*)&lB[(     srow) * 32 + soff] = vb0;
    *(bf16x8*)&lB[(64 + srow) * 32 + soff] = vb1;
    __syncthreads();  // staged tiles visible

    bf16x8 af[4], bfr[4];
#pragma unroll
    for (int i = 0; i < 4; ++i)
      af[i] = *(const bf16x8*)&lA[(wr + i * 16 + col0) * 32 + quad * 8];
#pragma unroll
    for (int j = 0; j < 4; ++j)
      bfr[j] = *(const bf16x8*)&lB[(wc + j * 16 + col0) * 32 + quad * 8];
#pragma unroll
    for (int i = 0; i < 4; ++i)
#pragma unroll
      for (int j = 0; j < 4; ++j)
        acc[i][j] = __builtin_amdgcn_mfma_f32_16x16x32_bf16(af[i], bfr[j], acc[i][j], 0, 0, 0);
  }

  // epilogue: C/D layout col=lane&15, row=quad*4+reg (m89-verified)
#pragma unroll
  for (int i = 0; i < 4; ++i)
#pragma unroll
    for (int j = 0; j < 4; ++j)
#pragma unroll
      for (int r = 0; r < 4; ++r) {
        int row = m0 + wr + i * 16 + quad * 4 + r;
        int col = n0 + wc + j * 16 + col0;
        C[(size_t)row * N + col] = (OutT)acc[i][j][r];
      }
}

// ---------------------------------------------------------------------------
// Kernel 4: sliding-window attention, one block per (b, h, 64-query group)
// context = 320 keys [qs-256, qs+63]; valid keys for query i: max(0,i-256)..i
// qkv row stride = 3200; gate logit at column 3072+h (fused in QKV GEMM).
// ---------------------------------------------------------------------------
#define NEG_BIG -1e30f
__global__ __launch_bounds__(256) void attn_kernel(
    const bf16* __restrict__ qkv, const float* __restrict__ bg,
    bf16* __restrict__ attnO) {
  __shared__ bf16 lQ[64 * 64];     // 8 KB
  __shared__ bf16 lKV[320 * 64];   // 40 KB: K[320][64] phase1, Vt[64][320] phase2
  __shared__ bf16 lP[4 * 16 * 32]; // 4 KB: per-wave P C->A layout scratch

  const int t = threadIdx.x;
  const int w = t >> 6, lane = t & 63;
  const int col0 = lane & 15, quad = lane >> 4;

  const int blk = blockIdx.x;
  const int g = blk & 63;
  const int h = (blk >> 6) & 15;
  const int bb = blk >> 10;
  const int qs = g * 64;

  const size_t rs = 3200;
  const bf16* qbase = qkv + ((size_t)bb * 4096) * rs + h * 64;

  // stage Q [64][64]
  for (int c = t; c < 64 * 8; c += 256) {
    int row = c >> 3, off = (c & 7) * 8;
    *(uint4*)&lQ[row * 64 + off] =
        *(const uint4*)(qbase + (size_t)(qs + row) * rs + off);
  }
  // stage K [320][64] (zero-fill j<0)
  for (int c = t; c < 320 * 8; c += 256) {
    int row = c >> 3, off = (c & 7) * 8;
    int j = qs - 256 + row;
    uint4 val = {0, 0, 0, 0};
    if (j >= 0) val = *(const uint4*)(qbase + 1024 + (size_t)j * rs + off);
    *(uint4*)&lKV[row * 64 + off] = val;
  }
  __syncthreads();

  // QK^T: wave w owns queries [w*16, w*16+16); S tile per wave: [16, 320]
  bf16x8 a0 = *(const bf16x8*)&lQ[(w * 16 + col0) * 64 + quad * 8];
  bf16x8 a1 = *(const bf16x8*)&lQ[(w * 16 + col0) * 64 + 32 + quad * 8];
  f32x4 s[20];
#pragma unroll
  for (int kt = 0; kt < 20; ++kt) {
    bf16x8 b0 = *(const bf16x8*)&lKV[(kt * 16 + col0) * 64 + quad * 8];
    bf16x8 b1 = *(const bf16x8*)&lKV[(kt * 16 + col0) * 64 + 32 + quad * 8];
    f32x4 z = {};
    z = __builtin_amdgcn_mfma_f32_16x16x32_bf16(a0, b0, z, 0, 0, 0);
    z = __builtin_amdgcn_mfma_f32_16x16x32_bf16(a1, b1, z, 0, 0, 0);
    s[kt] = z;
  }
  __syncthreads();  // all waves done reading K from lKV

  // stage V transposed: Vt[d][c] (zero-fill j<0) — overwrites lKV
  for (int c = t; c < 320 * 8; c += 256) {
    int row = c >> 3, off = (c & 7) * 8;
    int j = qs - 256 + row;
    bf16 tmp[8];
    if (j >= 0) {
      *(uint4*)tmp = *(const uint4*)(qbase + 2048 + (size_t)j * rs + off);
    } else {
#pragma unroll
      for (int d2 = 0; d2 < 8; ++d2) tmp[d2] = (bf16)0.f;
    }
#pragma unroll
    for (int d2 = 0; d2 < 8; ++d2) lKV[(off + d2) * 320 + row] = tmp[d2];
  }

  // softmax in registers (C layout: query row = quad*4+r, key col = kt*16+col0)
  float mrow[4] = {NEG_BIG, NEG_BIG, NEG_BIG, NEG_BIG};
  float lrow[4] = {0, 0, 0, 0};
#pragma unroll
  for (int kt = 0; kt < 20; ++kt) {
    int c = kt * 16 + col0;
#pragma unroll
    for (int r = 0; r < 4; ++r) {
      int ql = w * 16 + quad * 4 + r;
      bool valid = (c >= ql) && (c <= ql + 256) && (qs - 256 + c >= 0);
      float sv = valid ? s[kt][r] * 0.125f : NEG_BIG;  // scale = 1/sqrt(64)
      s[kt][r] = sv;
      mrow[r] = fmaxf(mrow[r], sv);
    }
  }
#pragma unroll
  for (int mm = 1; mm < 16; mm <<= 1)
#pragma unroll
    for (int r = 0; r < 4; ++r) mrow[r] = fmaxf(mrow[r], __shfl_xor(mrow[r], mm));
#pragma unroll
  for (int kt = 0; kt < 20; ++kt)
#pragma unroll
    for (int r = 0; r < 4; ++r) {
      float p = __expf(s[kt][r] - mrow[r]);
      s[kt][r] = p;
      lrow[r] += p;
    }
#pragma unroll
  for (int mm = 1; mm < 16; mm <<= 1)
#pragma unroll
    for (int r = 0; r < 4; ++r) lrow[r] += __shfl_xor(lrow[r], mm);

  __syncthreads();  // Vt staged

  // PV: per 32-key chunk, C->A layout transpose through per-wave LDS scratch.
  // lP slices are PER-WAVE; the DS pipe is in-order per wave, so a lgkmcnt
  // wait (no block barrier) orders the write->read within the wave.
  f32x4 o[4] = {};
  bf16* pw = &lP[w * 512];
#pragma unroll
  for (int kc = 0; kc < 10; ++kc) {
#pragma unroll
    for (int r = 0; r < 4; ++r) {
      pw[(quad * 4 + r) * 32 + col0]      = (bf16)s[2 * kc][r];
      pw[(quad * 4 + r) * 32 + 16 + col0] = (bf16)s[2 * kc + 1][r];
    }
    asm volatile("s_waitcnt lgkmcnt(0)" ::: "memory");
    bf16x8 pa = *(const bf16x8*)&pw[col0 * 32 + quad * 8];
#pragma unroll
    for (int n = 0; n < 4; ++n) {
      bf16x8 bv = *(const bf16x8*)&lKV[(n * 16 + col0) * 320 + kc * 32 + quad * 8];
      o[n] = __builtin_amdgcn_mfma_f32_16x16x32_bf16(pa, bv, o[n], 0, 0, 0);
    }
  }

  // epilogue: divide by l, apply sigmoid(gate_logit + bg[h]), write [b,s,h*64+d]
  const bf16* gbase = qkv + ((size_t)bb * 4096) * rs + 3072 + h;
  const float bgh = bg[h];
#pragma unroll
  for (int r = 0; r < 4; ++r) {
    int ql = w * 16 + quad * 4 + r;
    int srow = qs + ql;
    float logit = (float)gbase[(size_t)srow * rs] + bgh;
    float gate = 1.f / (1.f + __expf(-logit));
    float scale = gate / lrow[r];
#pragma unroll
    for (int n = 0; n < 4; ++n)
      attnO[((size_t)bb * 4096 + srow) * 1024 + h * 64 + n * 16 + col0] =
          (bf16)(o[n][r] * scale);
  }
}

// ---------------------------------------------------------------------------
extern "C" void kernel_launch(void* const* d_in, const int* in_sizes, int n_in,
                              void* d_out, int out_size, void* d_ws, size_t ws_size,
                              hipStream_t stream) {
  // Inputs fp32, mapped by flat element count (all six sizes distinct).
  const float *x = nullptr, *gamma = nullptr, *Wqkv = nullptr,
              *Wg = nullptr, *bg = nullptr, *Wout = nullptr;
  for (int i = 0; i < n_in; ++i) {
    switch (in_sizes[i]) {
      case 8388608: x     = (const float*)d_in[i]; break;
      case 1024:    gamma = (const float*)d_in[i]; break;
      case 3145728: Wqkv  = (const float*)d_in[i]; break;
      case 16384:   Wg    = (const float*)d_in[i]; break;
      case 16:      bg    = (const float*)d_in[i]; break;
      case 1048576: Wout  = (const float*)d_in[i]; break;
    }
  }
  float* out = (float*)d_out;  // fp32 output (verified R5)

  // BtAug = [WqkvT (3072 rows); WgT (16 rows); zero pad (112 rows)] x 1024
  char* ws = (char*)d_ws;
  bf16* qkv   = (bf16*)ws;  ws += (size_t)8192 * 3200 * 2;   // 52.4 MB (incl. gate logits)
  bf16* xn    = (bf16*)ws;                                    // 16 MB, dead after QKV GEMM
  bf16* attnO = (bf16*)ws;  ws += (size_t)8192 * 1024 * 2;   // aliases xn (stream-ordered)
  bf16* BtAug = (bf16*)ws;  ws += (size_t)3200 * 1024 * 2;   // 6.55 MB
  bf16* WoutT = (bf16*)ws;  ws += (size_t)1024 * 1024 * 2;   // total ~77.9 MB

  // zero the 112 pad rows of BtAug (re-poisoned to 0xAA before every call)
  hipMemsetAsync(BtAug + (size_t)3088 * 1024, 0, (size_t)112 * 1024 * 2, stream);

  rmsnorm_kernel<<<8192, 256, 0, stream>>>(x, gamma, xn);
  transpose_f32_bf16<<<dim3(3072 / 32, 1024 / 32), dim3(32, 8), 0, stream>>>(Wqkv, BtAug, 1024, 3072);
  wg_transpose<<<64, 256, 0, stream>>>(Wg, BtAug);
  transpose_f32_bf16<<<dim3(1024 / 32, 1024 / 32), dim3(32, 8), 0, stream>>>(Wout, WoutT, 1024, 1024);
  gemm_bt_128<bf16><<<dim3(3200 / 128, 8192 / 128), 256, 0, stream>>>(xn, BtAug, qkv, 8192, 3200, 1024);
  attn_kernel<<<2048, 256, 0, stream>>>(qkv, bg, attnO);
  gemm_bt_128<float><<<dim3(1024 / 128, 8192 / 128), 256, 0, stream>>>(attnO, WoutT, out, 8192, 1024, 1024);
}

// Round 7
// 293.981 us; speedup vs baseline: 1.1908x; 1.0300x over previous
//
#include <hip/hip_runtime.h>
#include <hip/hip_bf16.h>
#include <stdint.h>

typedef __bf16 bf16;
typedef __bf16 bf16x4 __attribute__((ext_vector_type(4)));
typedef __bf16 bf16x8 __attribute__((ext_vector_type(8)));
typedef float f32x4 __attribute__((ext_vector_type(4)));

#define GLOBAL_AS __attribute__((address_space(1)))
#define LDS_AS __attribute__((address_space(3)))

__device__ __forceinline__ void g2lds16(const bf16* g, bf16* l) {
  // async global->LDS DMA, 16 B/lane; LDS dest = wave-uniform base + lane*16
  __builtin_amdgcn_global_load_lds((const GLOBAL_AS void*)g, (LDS_AS void*)l, 16, 0, 0);
}

// ---------------------------------------------------------------------------
// Kernel 1: pure streaming RMSNorm (F.normalize * sqrt(1024) * gamma).
// ---------------------------------------------------------------------------
__global__ __launch_bounds__(256) void rmsnorm_kernel(
    const float* __restrict__ x, const float* __restrict__ gamma,
    bf16* __restrict__ xn) {
  __shared__ float wss[4];
  const int t = threadIdx.x;
  const size_t row = blockIdx.x;
  const float* xr = x + row * 1024;

  float4 xv = *(const float4*)&xr[t * 4];
  float v[4] = {xv.x, xv.y, xv.z, xv.w};
  float ss = v[0]*v[0] + v[1]*v[1] + v[2]*v[2] + v[3]*v[3];
#pragma unroll
  for (int mm = 1; mm < 64; mm <<= 1) ss += __shfl_xor(ss, mm);
  if ((t & 63) == 0) wss[t >> 6] = ss;
  __syncthreads();
  ss = wss[0] + wss[1] + wss[2] + wss[3];
  float inv = 32.0f / sqrtf(fmaxf(ss, 1e-24f));  // sqrt(1024)=32

  float4 gv = *(const float4*)&gamma[t * 4];
  float gvv[4] = {gv.x, gv.y, gv.z, gv.w};
  bf16x4 outv;
#pragma unroll
  for (int i = 0; i < 4; ++i) outv[i] = (bf16)(v[i] * inv * gvv[i]);
  *(bf16x4*)&xn[row * 1024 + t * 4] = outv;
}

// ---------------------------------------------------------------------------
// Kernel 2: fp32 -> bf16 transpose (for B^T GEMM operand), 32x32 tiles
// ---------------------------------------------------------------------------
__global__ void transpose_f32_bf16(const float* __restrict__ in, bf16* __restrict__ out,
                                   int R, int C) {
  __shared__ bf16 tile[32][33];
  const int tx = threadIdx.x, ty = threadIdx.y;  // 32 x 8
  const int c0 = blockIdx.x * 32, r0 = blockIdx.y * 32;
#pragma unroll
  for (int i = 0; i < 32; i += 8)
    tile[ty + i][tx] = (bf16)in[(size_t)(r0 + ty + i) * C + c0 + tx];
  __syncthreads();
#pragma unroll
  for (int i = 0; i < 32; i += 8)
    out[(size_t)(c0 + ty + i) * R + r0 + tx] = tile[tx][ty + i];
}

// Wg [1024,16] -> rows 3072..3087 of BtAug [3200,1024]. Tiny (16K elements).
__global__ __launch_bounds__(256) void wg_transpose(const float* __restrict__ Wg,
                                                    bf16* __restrict__ BtAug) {
  int idx = blockIdx.x * 256 + threadIdx.x;   // [0, 16384)
  int n = idx >> 10, k = idx & 1023;
  BtAug[(size_t)(3072 + n) * 1024 + k] = (bf16)Wg[(size_t)k * 16 + n];
}

// ---------------------------------------------------------------------------
// Kernel 3: MFMA bf16 GEMM, C[M,N] = A[M,K] @ Bt[N,K]^T, 128x128 tile, BK=32.
// m97 staging: global_load_lds width=16 (no VGPR round-trip), plus XOR
// chunk-swizzle (chunk_lds = chunk_g ^ ((row>>1)&3)) so ds_read_b128 fragment
// reads hit all 8 bank-groups (2-way aliasing only = free; was 8-way).
// Swizzle permutes 16B chunks WITHIN a 64B row: same cache line, coalescing
// unchanged, and expressible through the per-lane source pointer of the DMA.
// ---------------------------------------------------------------------------
template <typename OutT>
__global__ __launch_bounds__(256) void gemm_bt_128(
    const bf16* __restrict__ A, const bf16* __restrict__ Bt,
    OutT* __restrict__ C, int M, int N, int K) {
  __shared__ bf16 lA[128 * 32];
  __shared__ bf16 lB[128 * 32];
  const int t = threadIdx.x;
  const int w = t >> 6, lane = t & 63;
  const int col0 = lane & 15, quad = lane >> 4;
  const int m0 = blockIdx.y * 128, n0 = blockIdx.x * 128;
  const int wr = (w >> 1) * 64, wc = (w & 1) * 64;

  // staging: lane covers LDS (row=srow or 64+srow, chunk=t&3); its global
  // source chunk is swizzled. f(row)=(row>>1)&3; f(64+srow)==f(srow).
  const int srow = t >> 2;                               // 0..63
  const int soff = (((t & 3) ^ ((srow >> 1) & 3)) << 3); // swizzled k-offset

  f32x4 acc[4][4] = {};

  for (int k0 = 0; k0 < K; k0 += 32) {
    __syncthreads();  // previous iteration's LDS reads done
    g2lds16(A  + (size_t)(m0 +      srow) * K + k0 + soff, &lA[w * 512]);
    g2lds16(A  + (size_t)(m0 + 64 + srow) * K + k0 + soff, &lA[2048 + w * 512]);
    g2lds16(Bt + (size_t)(n0 +      srow) * K + k0 + soff, &lB[w * 512]);
    g2lds16(Bt + (size_t)(n0 + 64 + srow) * K + k0 + soff, &lB[2048 + w * 512]);
    __syncthreads();  // drains vmcnt(0): staged tiles visible

    bf16x8 af[4], bfr[4];
#pragma unroll
    for (int i = 0; i < 4; ++i) {
      int row = wr + i * 16 + col0;
      af[i] = *(const bf16x8*)&lA[row * 32 + ((quad ^ ((row >> 1) & 3)) << 3)];
    }
#pragma unroll
    for (int j = 0; j < 4; ++j) {
      int row = wc + j * 16 + col0;
      bfr[j] = *(const bf16x8*)&lB[row * 32 + ((quad ^ ((row >> 1) & 3)) << 3)];
    }
#pragma unroll
    for (int i = 0; i < 4; ++i)
#pragma unroll
      for (int j = 0; j < 4; ++j)
        acc[i][j] = __builtin_amdgcn_mfma_f32_16x16x32_bf16(af[i], bfr[j], acc[i][j], 0, 0, 0);
  }

  // epilogue: C/D layout col=lane&15, row=quad*4+reg
#pragma unroll
  for (int i = 0; i < 4; ++i)
#pragma unroll
    for (int j = 0; j < 4; ++j)
#pragma unroll
      for (int r = 0; r < 4; ++r) {
        int row = m0 + wr + i * 16 + quad * 4 + r;
        int col = n0 + wc + j * 16 + col0;
        C[(size_t)row * N + col] = (OutT)acc[i][j][r];
      }
}

// ---------------------------------------------------------------------------
// Kernel 4: sliding-window attention, one block per (b, h, 64-query group)
// context = 320 keys [qs-256, qs+63]; valid keys for query i: max(0,i-256)..i
// qkv row stride = 3200; gate logit at column 3072+h (fused in QKV GEMM).
// ---------------------------------------------------------------------------
#define NEG_BIG -1e30f
__global__ __launch_bounds__(256) void attn_kernel(
    const bf16* __restrict__ qkv, const float* __restrict__ bg,
    bf16* __restrict__ attnO) {
  __shared__ bf16 lQ[64 * 64];     // 8 KB
  __shared__ bf16 lKV[320 * 64];   // 40 KB: K[320][64] phase1, Vt[64][320] phase2
  __shared__ bf16 lP[4 * 16 * 32]; // 4 KB: per-wave P C->A layout scratch

  const int t = threadIdx.x;
  const int w = t >> 6, lane = t & 63;
  const int col0 = lane & 15, quad = lane >> 4;

  const int blk = blockIdx.x;
  const int g = blk & 63;
  const int h = (blk >> 6) & 15;
  const int bb = blk >> 10;
  const int qs = g * 64;

  const size_t rs = 3200;
  const bf16* qbase = qkv + ((size_t)bb * 4096) * rs + h * 64;

  // stage Q [64][64]
  for (int c = t; c < 64 * 8; c += 256) {
    int row = c >> 3, off = (c & 7) * 8;
    *(uint4*)&lQ[row * 64 + off] =
        *(const uint4*)(qbase + (size_t)(qs + row) * rs + off);
  }
  // stage K [320][64] (zero-fill j<0)
  for (int c = t; c < 320 * 8; c += 256) {
    int row = c >> 3, off = (c & 7) * 8;
    int j = qs - 256 + row;
    uint4 val = {0, 0, 0, 0};
    if (j >= 0) val = *(const uint4*)(qbase + 1024 + (size_t)j * rs + off);
    *(uint4*)&lKV[row * 64 + off] = val;
  }
  __syncthreads();

  // QK^T: wave w owns queries [w*16, w*16+16); S tile per wave: [16, 320]
  bf16x8 a0 = *(const bf16x8*)&lQ[(w * 16 + col0) * 64 + quad * 8];
  bf16x8 a1 = *(const bf16x8*)&lQ[(w * 16 + col0) * 64 + 32 + quad * 8];
  f32x4 s[20];
#pragma unroll
  for (int kt = 0; kt < 20; ++kt) {
    bf16x8 b0 = *(const bf16x8*)&lKV[(kt * 16 + col0) * 64 + quad * 8];
    bf16x8 b1 = *(const bf16x8*)&lKV[(kt * 16 + col0) * 64 + 32 + quad * 8];
    f32x4 z = {};
    z = __builtin_amdgcn_mfma_f32_16x16x32_bf16(a0, b0, z, 0, 0, 0);
    z = __builtin_amdgcn_mfma_f32_16x16x32_bf16(a1, b1, z, 0, 0, 0);
    s[kt] = z;
  }
  __syncthreads();  // all waves done reading K from lKV

  // stage V transposed: Vt[d][c] (zero-fill j<0) — overwrites lKV
  for (int c = t; c < 320 * 8; c += 256) {
    int row = c >> 3, off = (c & 7) * 8;
    int j = qs - 256 + row;
    bf16 tmp[8];
    if (j >= 0) {
      *(uint4*)tmp = *(const uint4*)(qbase + 2048 + (size_t)j * rs + off);
    } else {
#pragma unroll
      for (int d2 = 0; d2 < 8; ++d2) tmp[d2] = (bf16)0.f;
    }
#pragma unroll
    for (int d2 = 0; d2 < 8; ++d2) lKV[(off + d2) * 320 + row] = tmp[d2];
  }

  // softmax in registers (C layout: query row = quad*4+r, key col = kt*16+col0)
  float mrow[4] = {NEG_BIG, NEG_BIG, NEG_BIG, NEG_BIG};
  float lrow[4] = {0, 0, 0, 0};
#pragma unroll
  for (int kt = 0; kt < 20; ++kt) {
    int c = kt * 16 + col0;
#pragma unroll
    for (int r = 0; r < 4; ++r) {
      int ql = w * 16 + quad * 4 + r;
      bool valid = (c >= ql) && (c <= ql + 256) && (qs - 256 + c >= 0);
      float sv = valid ? s[kt][r] * 0.125f : NEG_BIG;  // scale = 1/sqrt(64)
      s[kt][r] = sv;
      mrow[r] = fmaxf(mrow[r], sv);
    }
  }
#pragma unroll
  for (int mm = 1; mm < 16; mm <<= 1)
#pragma unroll
    for (int r = 0; r < 4; ++r) mrow[r] = fmaxf(mrow[r], __shfl_xor(mrow[r], mm));
#pragma unroll
  for (int kt = 0; kt < 20; ++kt)
#pragma unroll
    for (int r = 0; r < 4; ++r) {
      float p = __expf(s[kt][r] - mrow[r]);
      s[kt][r] = p;
      lrow[r] += p;
    }
#pragma unroll
  for (int mm = 1; mm < 16; mm <<= 1)
#pragma unroll
    for (int r = 0; r < 4; ++r) lrow[r] += __shfl_xor(lrow[r], mm);

  __syncthreads();  // Vt staged

  // PV: per 32-key chunk, C->A layout transpose through per-wave LDS scratch.
  // lP slices are PER-WAVE; DS pipe is in-order per wave, so lgkmcnt(0)
  // (no block barrier) orders the write->read within the wave.
  f32x4 o[4] = {};
  bf16* pw = &lP[w * 512];
#pragma unroll
  for (int kc = 0; kc < 10; ++kc) {
#pragma unroll
    for (int r = 0; r < 4; ++r) {
      pw[(quad * 4 + r) * 32 + col0]      = (bf16)s[2 * kc][r];
      pw[(quad * 4 + r) * 32 + 16 + col0] = (bf16)s[2 * kc + 1][r];
    }
    asm volatile("s_waitcnt lgkmcnt(0)" ::: "memory");
    bf16x8 pa = *(const bf16x8*)&pw[col0 * 32 + quad * 8];
#pragma unroll
    for (int n = 0; n < 4; ++n) {
      bf16x8 bv = *(const bf16x8*)&lKV[(n * 16 + col0) * 320 + kc * 32 + quad * 8];
      o[n] = __builtin_amdgcn_mfma_f32_16x16x32_bf16(pa, bv, o[n], 0, 0, 0);
    }
  }

  // epilogue: divide by l, apply sigmoid(gate_logit + bg[h]), write [b,s,h*64+d]
  const bf16* gbase = qkv + ((size_t)bb * 4096) * rs + 3072 + h;
  const float bgh = bg[h];
#pragma unroll
  for (int r = 0; r < 4; ++r) {
    int ql = w * 16 + quad * 4 + r;
    int srow = qs + ql;
    float logit = (float)gbase[(size_t)srow * rs] + bgh;
    float gate = 1.f / (1.f + __expf(-logit));
    float scale = gate / lrow[r];
#pragma unroll
    for (int n = 0; n < 4; ++n)
      attnO[((size_t)bb * 4096 + srow) * 1024 + h * 64 + n * 16 + col0] =
          (bf16)(o[n][r] * scale);
  }
}

// ---------------------------------------------------------------------------
extern "C" void kernel_launch(void* const* d_in, const int* in_sizes, int n_in,
                              void* d_out, int out_size, void* d_ws, size_t ws_size,
                              hipStream_t stream) {
  // Inputs fp32, mapped by flat element count (all six sizes distinct).
  const float *x = nullptr, *gamma = nullptr, *Wqkv = nullptr,
              *Wg = nullptr, *bg = nullptr, *Wout = nullptr;
  for (int i = 0; i < n_in; ++i) {
    switch (in_sizes[i]) {
      case 8388608: x     = (const float*)d_in[i]; break;
      case 1024:    gamma = (const float*)d_in[i]; break;
      case 3145728: Wqkv  = (const float*)d_in[i]; break;
      case 16384:   Wg    = (const float*)d_in[i]; break;
      case 16:      bg    = (const float*)d_in[i]; break;
      case 1048576: Wout  = (const float*)d_in[i]; break;
    }
  }
  float* out = (float*)d_out;  // fp32 output (verified R5)

  // BtAug = [WqkvT (3072 rows); WgT (16 rows); zero pad (112 rows)] x 1024
  char* ws = (char*)d_ws;
  bf16* qkv   = (bf16*)ws;  ws += (size_t)8192 * 3200 * 2;   // 52.4 MB (incl. gate logits)
  bf16* xn    = (bf16*)ws;                                    // 16 MB, dead after QKV GEMM
  bf16* attnO = (bf16*)ws;  ws += (size_t)8192 * 1024 * 2;   // aliases xn (stream-ordered)
  bf16* BtAug = (bf16*)ws;  ws += (size_t)3200 * 1024 * 2;   // 6.55 MB
  bf16* WoutT = (bf16*)ws;  ws += (size_t)1024 * 1024 * 2;   // total ~77.9 MB

  // zero the 112 pad rows of BtAug (re-poisoned to 0xAA before every call)
  hipMemsetAsync(BtAug + (size_t)3088 * 1024, 0, (size_t)112 * 1024 * 2, stream);

  rmsnorm_kernel<<<8192, 256, 0, stream>>>(x, gamma, xn);
  transpose_f32_bf16<<<dim3(3072 / 32, 1024 / 32), dim3(32, 8), 0, stream>>>(Wqkv, BtAug, 1024, 3072);
  wg_transpose<<<64, 256, 0, stream>>>(Wg, BtAug);
  transpose_f32_bf16<<<dim3(1024 / 32, 1024 / 32), dim3(32, 8), 0, stream>>>(Wout, WoutT, 1024, 1024);
  gemm_bt_128<bf16><<<dim3(3200 / 128, 8192 / 128), 256, 0, stream>>>(xn, BtAug, qkv, 8192, 3200, 1024);
  attn_kernel<<<2048, 256, 0, stream>>>(qkv, bg, attnO);
  gemm_bt_128<float><<<dim3(1024 / 128, 8192 / 128), 256, 0, stream>>>(attnO, WoutT, out, 8192, 1024, 1024);
}

// Round 8
// 273.697 us; speedup vs baseline: 1.2791x; 1.0741x over previous
//
#include <hip/hip_runtime.h>
#include <hip/hip_bf16.h>
#include <stdint.h>

typedef __bf16 bf16;
typedef __bf16 bf16x4 __attribute__((ext_vector_type(4)));
typedef __bf16 bf16x8 __attribute__((ext_vector_type(8)));
typedef float f32x4 __attribute__((ext_vector_type(4)));

#define GLOBAL_AS __attribute__((address_space(1)))
#define LDS_AS __attribute__((address_space(3)))

__device__ __forceinline__ void g2lds16(const bf16* g, bf16* l) {
  // async global->LDS DMA, 16 B/lane; LDS dest = wave-uniform base + lane*16
  __builtin_amdgcn_global_load_lds((const GLOBAL_AS void*)g, (LDS_AS void*)l, 16, 0, 0);
}

// ---------------------------------------------------------------------------
// Kernel 1: pure streaming RMSNorm (F.normalize * sqrt(1024) * gamma).
// ---------------------------------------------------------------------------
__global__ __launch_bounds__(256) void rmsnorm_kernel(
    const float* __restrict__ x, const float* __restrict__ gamma,
    bf16* __restrict__ xn) {
  __shared__ float wss[4];
  const int t = threadIdx.x;
  const size_t row = blockIdx.x;
  const float* xr = x + row * 1024;

  float4 xv = *(const float4*)&xr[t * 4];
  float v[4] = {xv.x, xv.y, xv.z, xv.w};
  float ss = v[0]*v[0] + v[1]*v[1] + v[2]*v[2] + v[3]*v[3];
#pragma unroll
  for (int mm = 1; mm < 64; mm <<= 1) ss += __shfl_xor(ss, mm);
  if ((t & 63) == 0) wss[t >> 6] = ss;
  __syncthreads();
  ss = wss[0] + wss[1] + wss[2] + wss[3];
  float inv = 32.0f / sqrtf(fmaxf(ss, 1e-24f));  // sqrt(1024)=32

  float4 gv = *(const float4*)&gamma[t * 4];
  float gvv[4] = {gv.x, gv.y, gv.z, gv.w};
  bf16x4 outv;
#pragma unroll
  for (int i = 0; i < 4; ++i) outv[i] = (bf16)(v[i] * inv * gvv[i]);
  *(bf16x4*)&xn[row * 1024 + t * 4] = outv;
}

// ---------------------------------------------------------------------------
// Kernel 2: fp32 -> bf16 transpose (for B^T GEMM operand), 32x32 tiles
// ---------------------------------------------------------------------------
__global__ void transpose_f32_bf16(const float* __restrict__ in, bf16* __restrict__ out,
                                   int R, int C) {
  __shared__ bf16 tile[32][33];
  const int tx = threadIdx.x, ty = threadIdx.y;  // 32 x 8
  const int c0 = blockIdx.x * 32, r0 = blockIdx.y * 32;
#pragma unroll
  for (int i = 0; i < 32; i += 8)
    tile[ty + i][tx] = (bf16)in[(size_t)(r0 + ty + i) * C + c0 + tx];
  __syncthreads();
#pragma unroll
  for (int i = 0; i < 32; i += 8)
    out[(size_t)(c0 + ty + i) * R + r0 + tx] = tile[tx][ty + i];
}

// Wg [1024,16] -> rows 3072..3087 of BtAug [3200,1024]. Tiny (16K elements).
__global__ __launch_bounds__(256) void wg_transpose(const float* __restrict__ Wg,
                                                    bf16* __restrict__ BtAug) {
  int idx = blockIdx.x * 256 + threadIdx.x;   // [0, 16384)
  int n = idx >> 10, k = idx & 1023;
  BtAug[(size_t)(3072 + n) * 1024 + k] = (bf16)Wg[(size_t)k * 16 + n];
}

// ---------------------------------------------------------------------------
// Kernel 3: MFMA bf16 GEMM, C[M,N] = A[M,K] @ Bt[N,K]^T, 128x128 tile, BK=64.
// BK=64 halves the barrier-drain events vs BK=32 (same staging/ds/MFMA totals;
// LDS 32 KB keeps the VGPR-bound 3 blocks/CU). Rows are 128 B (≡0 mod 32
// banks) so swizzle is ck' = ck ^ (row&7): per-quad-phase 2-way = free.
// ---------------------------------------------------------------------------
template <typename OutT>
__global__ __launch_bounds__(256) void gemm_bt_128(
    const bf16* __restrict__ A, const bf16* __restrict__ Bt,
    OutT* __restrict__ C, int M, int N, int K) {
  __shared__ bf16 lA[128 * 64];
  __shared__ bf16 lB[128 * 64];
  const int t = threadIdx.x;
  const int w = t >> 6, lane = t & 63;
  const int col0 = lane & 15, quad = lane >> 4;
  const int m0 = blockIdx.y * 128, n0 = blockIdx.x * 128;
  const int wr = (w >> 1) * 64, wc = (w & 1) * 64;

  // staging: 4 calls/tile; call c covers rows c*32..c*32+31 (this wave: +w*8).
  const int lrow = t >> 3;                          // 0..31 (includes w*8)
  const int sswz = (((t & 7) ^ (lrow & 7)) << 3);   // swizzled src k-offset

  f32x4 acc[4][4] = {};

  for (int k0 = 0; k0 < K; k0 += 64) {
    __syncthreads();  // previous iteration's LDS reads done
#pragma unroll
    for (int c = 0; c < 4; ++c) {
      g2lds16(A  + (size_t)(m0 + c * 32 + lrow) * K + k0 + sswz, &lA[c * 2048 + w * 512]);
      g2lds16(Bt + (size_t)(n0 + c * 32 + lrow) * K + k0 + sswz, &lB[c * 2048 + w * 512]);
    }
    __syncthreads();  // drains vmcnt(0): staged tiles visible

#pragma unroll
    for (int kh = 0; kh < 2; ++kh) {
      bf16x8 af[4], bfr[4];
#pragma unroll
      for (int i = 0; i < 4; ++i) {
        int row = wr + i * 16 + col0;
        af[i] = *(const bf16x8*)&lA[row * 64 + (((kh * 4 + quad) ^ (row & 7)) << 3)];
      }
#pragma unroll
      for (int j = 0; j < 4; ++j) {
        int row = wc + j * 16 + col0;
        bfr[j] = *(const bf16x8*)&lB[row * 64 + (((kh * 4 + quad) ^ (row & 7)) << 3)];
      }
#pragma unroll
      for (int i = 0; i < 4; ++i)
#pragma unroll
        for (int j = 0; j < 4; ++j)
          acc[i][j] = __builtin_amdgcn_mfma_f32_16x16x32_bf16(af[i], bfr[j], acc[i][j], 0, 0, 0);
    }
  }

  // epilogue: C/D layout col=lane&15, row=quad*4+reg
#pragma unroll
  for (int i = 0; i < 4; ++i)
#pragma unroll
    for (int j = 0; j < 4; ++j)
#pragma unroll
      for (int r = 0; r < 4; ++r) {
        int row = m0 + wr + i * 16 + quad * 4 + r;
        int col = n0 + wc + j * 16 + col0;
        C[(size_t)row * N + col] = (OutT)acc[i][j][r];
      }
}

// ---------------------------------------------------------------------------
// Kernel 4: sliding-window attention, one block per (b, h, 64-query group).
// All LDS tiles have row strides ≡ 0 mod 32 banks -> every fragment access
// was 16-way conflicted. Fixes: XOR chunk swizzle ck^=row&7 on Q/K; Vt staged
// key-major (lane=key) with ck^=d&7 (scatter now 2-way, PV reads 2-way).
// ---------------------------------------------------------------------------
#define NEG_BIG -1e30f
__global__ __launch_bounds__(256) void attn_kernel(
    const bf16* __restrict__ qkv, const float* __restrict__ bg,
    bf16* __restrict__ attnO) {
  __shared__ bf16 lQ[64 * 64];     // 8 KB,  swizzled chunks
  __shared__ bf16 lKV[320 * 64];   // 40 KB: K[320][64] phase1, Vt[64][320] phase2
  __shared__ bf16 lP[4 * 16 * 32]; // 4 KB: per-wave P C->A layout scratch

  const int t = threadIdx.x;
  const int w = t >> 6, lane = t & 63;
  const int col0 = lane & 15, quad = lane >> 4;

  const int blk = blockIdx.x;
  const int g = blk & 63;
  const int h = (blk >> 6) & 15;
  const int bb = blk >> 10;
  const int qs = g * 64;

  const size_t rs = 3200;
  const bf16* qbase = qkv + ((size_t)bb * 4096) * rs + h * 64;

  // stage Q [64][64], chunk-swizzled: LDS[row][ck^(row&7)] = G[row][ck]
  for (int c = t; c < 64 * 8; c += 256) {
    int row = c >> 3, ck = c & 7;
    *(uint4*)&lQ[row * 64 + ((ck ^ (row & 7)) << 3)] =
        *(const uint4*)(qbase + (size_t)(qs + row) * rs + ck * 8);
  }
  // stage K [320][64], chunk-swizzled (zero-fill j<0)
  for (int c = t; c < 320 * 8; c += 256) {
    int row = c >> 3, ck = c & 7;
    int j = qs - 256 + row;
    uint4 val = {0, 0, 0, 0};
    if (j >= 0) val = *(const uint4*)(qbase + 1024 + (size_t)j * rs + ck * 8);
    *(uint4*)&lKV[row * 64 + ((ck ^ (row & 7)) << 3)] = val;
  }
  __syncthreads();

  // QK^T: wave w owns queries [w*16, w*16+16); S tile per wave: [16, 320]
  const int qrow = w * 16 + col0;
  bf16x8 a0 = *(const bf16x8*)&lQ[qrow * 64 + ((quad ^ (qrow & 7)) << 3)];
  bf16x8 a1 = *(const bf16x8*)&lQ[qrow * 64 + (((4 + quad) ^ (qrow & 7)) << 3)];
  f32x4 s[20];
#pragma unroll
  for (int kt = 0; kt < 20; ++kt) {
    int krow = kt * 16 + col0;
    bf16x8 b0 = *(const bf16x8*)&lKV[krow * 64 + ((quad ^ (krow & 7)) << 3)];
    bf16x8 b1 = *(const bf16x8*)&lKV[krow * 64 + (((4 + quad) ^ (krow & 7)) << 3)];
    f32x4 z = {};
    z = __builtin_amdgcn_mfma_f32_16x16x32_bf16(a0, b0, z, 0, 0, 0);
    z = __builtin_amdgcn_mfma_f32_16x16x32_bf16(a1, b1, z, 0, 0, 0);
    s[kt] = z;
  }
  __syncthreads();  // all waves done reading K from lKV

  // stage V transposed Vt[d][c] over lKV, key-major lanes + chunk swizzle:
  // thread: key jl = t&31 (contiguous), d-group dg = t>>5 (8 dims).
  // LDS[d][ (ck ^ (d&7))*8 + within ] ; scatter is 2-way (free).
  {
    const int jl = t & 31, dg = t >> 5;
#pragma unroll
    for (int cc = 0; cc < 10; ++cc) {
      int j = qs - 256 + cc * 32 + jl;
      bf16 tmp[8];
      if (j >= 0) {
        *(uint4*)tmp = *(const uint4*)(qbase + 2048 + (size_t)j * rs + dg * 8);
      } else {
#pragma unroll
        for (int d2 = 0; d2 < 8; ++d2) tmp[d2] = (bf16)0.f;
      }
      int ck = cc * 4 + (jl >> 3);     // 16B chunk index along keys (0..39)
      int wi = jl & 7;                 // element within chunk
#pragma unroll
      for (int d2 = 0; d2 < 8; ++d2) {
        int d = dg * 8 + d2;
        lKV[d * 320 + ((ck ^ (d & 7)) << 3) + wi] = tmp[d2];
      }
    }
  }

  // softmax in registers (C layout: query row = quad*4+r, key col = kt*16+col0)
  float mrow[4] = {NEG_BIG, NEG_BIG, NEG_BIG, NEG_BIG};
  float lrow[4] = {0, 0, 0, 0};
#pragma unroll
  for (int kt = 0; kt < 20; ++kt) {
    int c = kt * 16 + col0;
#pragma unroll
    for (int r = 0; r < 4; ++r) {
      int ql = w * 16 + quad * 4 + r;
      bool valid = (c >= ql) && (c <= ql + 256) && (qs - 256 + c >= 0);
      float sv = valid ? s[kt][r] * 0.125f : NEG_BIG;  // scale = 1/sqrt(64)
      s[kt][r] = sv;
      mrow[r] = fmaxf(mrow[r], sv);
    }
  }
#pragma unroll
  for (int mm = 1; mm < 16; mm <<= 1)
#pragma unroll
    for (int r = 0; r < 4; ++r) mrow[r] = fmaxf(mrow[r], __shfl_xor(mrow[r], mm));
#pragma unroll
  for (int kt = 0; kt < 20; ++kt)
#pragma unroll
    for (int r = 0; r < 4; ++r) {
      float p = __expf(s[kt][r] - mrow[r]);
      s[kt][r] = p;
      lrow[r] += p;
    }
#pragma unroll
  for (int mm = 1; mm < 16; mm <<= 1)
#pragma unroll
    for (int r = 0; r < 4; ++r) lrow[r] += __shfl_xor(lrow[r], mm);

  __syncthreads();  // Vt staged

  // PV: per 32-key chunk, C->A transpose of P through per-wave LDS scratch.
  // lP is per-wave; DS pipe is in-order per wave -> lgkmcnt(0) suffices.
  f32x4 o[4] = {};
  bf16* pw = &lP[w * 512];
#pragma unroll
  for (int kc = 0; kc < 10; ++kc) {
#pragma unroll
    for (int r = 0; r < 4; ++r) {
      pw[(quad * 4 + r) * 32 + col0]      = (bf16)s[2 * kc][r];
      pw[(quad * 4 + r) * 32 + 16 + col0] = (bf16)s[2 * kc + 1][r];
    }
    asm volatile("s_waitcnt lgkmcnt(0)" ::: "memory");
    bf16x8 pa = *(const bf16x8*)&pw[col0 * 32 + quad * 8];
#pragma unroll
    for (int n = 0; n < 4; ++n) {
      int d = n * 16 + col0;
      bf16x8 bv = *(const bf16x8*)&lKV[d * 320 + (((kc * 4 + quad) ^ (d & 7)) << 3)];
      o[n] = __builtin_amdgcn_mfma_f32_16x16x32_bf16(pa, bv, o[n], 0, 0, 0);
    }
  }

  // epilogue: divide by l, apply sigmoid(gate_logit + bg[h]), write [b,s,h*64+d]
  const bf16* gbase = qkv + ((size_t)bb * 4096) * rs + 3072 + h;
  const float bgh = bg[h];
#pragma unroll
  for (int r = 0; r < 4; ++r) {
    int ql = w * 16 + quad * 4 + r;
    int srow = qs + ql;
    float logit = (float)gbase[(size_t)srow * rs] + bgh;
    float gate = 1.f / (1.f + __expf(-logit));
    float scale = gate / lrow[r];
#pragma unroll
    for (int n = 0; n < 4; ++n)
      attnO[((size_t)bb * 4096 + srow) * 1024 + h * 64 + n * 16 + col0] =
          (bf16)(o[n][r] * scale);
  }
}

// ---------------------------------------------------------------------------
extern "C" void kernel_launch(void* const* d_in, const int* in_sizes, int n_in,
                              void* d_out, int out_size, void* d_ws, size_t ws_size,
                              hipStream_t stream) {
  // Inputs fp32, mapped by flat element count (all six sizes distinct).
  const float *x = nullptr, *gamma = nullptr, *Wqkv = nullptr,
              *Wg = nullptr, *bg = nullptr, *Wout = nullptr;
  for (int i = 0; i < n_in; ++i) {
    switch (in_sizes[i]) {
      case 8388608: x     = (const float*)d_in[i]; break;
      case 1024:    gamma = (const float*)d_in[i]; break;
      case 3145728: Wqkv  = (const float*)d_in[i]; break;
      case 16384:   Wg    = (const float*)d_in[i]; break;
      case 16:      bg    = (const float*)d_in[i]; break;
      case 1048576: Wout  = (const float*)d_in[i]; break;
    }
  }
  float* out = (float*)d_out;  // fp32 output (verified R5)

  // BtAug = [WqkvT (3072 rows); WgT (16 rows); zero pad (112 rows)] x 1024
  char* ws = (char*)d_ws;
  bf16* qkv   = (bf16*)ws;  ws += (size_t)8192 * 3200 * 2;   // 52.4 MB (incl. gate logits)
  bf16* xn    = (bf16*)ws;                                    // 16 MB, dead after QKV GEMM
  bf16* attnO = (bf16*)ws;  ws += (size_t)8192 * 1024 * 2;   // aliases xn (stream-ordered)
  bf16* BtAug = (bf16*)ws;  ws += (size_t)3200 * 1024 * 2;   // 6.55 MB
  bf16* WoutT = (bf16*)ws;  ws += (size_t)1024 * 1024 * 2;   // total ~77.9 MB

  // zero the 112 pad rows of BtAug (re-poisoned to 0xAA before every call)
  hipMemsetAsync(BtAug + (size_t)3088 * 1024, 0, (size_t)112 * 1024 * 2, stream);

  rmsnorm_kernel<<<8192, 256, 0, stream>>>(x, gamma, xn);
  transpose_f32_bf16<<<dim3(3072 / 32, 1024 / 32), dim3(32, 8), 0, stream>>>(Wqkv, BtAug, 1024, 3072);
  wg_transpose<<<64, 256, 0, stream>>>(Wg, BtAug);
  transpose_f32_bf16<<<dim3(1024 / 32, 1024 / 32), dim3(32, 8), 0, stream>>>(Wout, WoutT, 1024, 1024);
  gemm_bt_128<bf16><<<dim3(3200 / 128, 8192 / 128), 256, 0, stream>>>(xn, BtAug, qkv, 8192, 3200, 1024);
  attn_kernel<<<2048, 256, 0, stream>>>(qkv, bg, attnO);
  gemm_bt_128<float><<<dim3(1024 / 128, 8192 / 128), 256, 0, stream>>>(attnO, WoutT, out, 8192, 1024, 1024);
}